// Round 5
// baseline (773.118 us; speedup 1.0000x reference)
//
#include <hip/hip_runtime.h>
#include <stdint.h>

typedef unsigned short u16;
typedef __attribute__((ext_vector_type(8))) short bf16x8;
typedef __attribute__((ext_vector_type(4))) float f32x4;

#define MFMA_BF16(a,b,c) __builtin_amdgcn_mfma_f32_16x16x32_bf16((a),(b),(c),0,0,0)

__device__ inline u16 f2bf(float f) {
  uint32_t u = __builtin_bit_cast(uint32_t, f);
  u = (u + 0x7FFFu + ((u >> 16) & 1u)) >> 16;
  return (u16)u;
}
__device__ inline float bf2f(u16 h) {
  uint32_t u = ((uint32_t)h) << 16;
  return __builtin_bit_cast(float, u);
}

// ---------------- fp32 -> bf16 conversion ----------------
__global__ __launch_bounds__(256) void cvt_kernel(const float* __restrict__ src,
                                                  u16* __restrict__ dst, int n4) {
  int i = blockIdx.x * 256 + threadIdx.x;
  if (i >= n4) return;
  float4 v = reinterpret_cast<const float4*>(src)[i];
  uint2 o;
  o.x = (uint32_t)f2bf(v.x) | ((uint32_t)f2bf(v.y) << 16);
  o.y = (uint32_t)f2bf(v.z) | ((uint32_t)f2bf(v.w) << 16);
  reinterpret_cast<uint2*>(dst)[i] = o;
}

// ---------------- GEMM: C[M][N] = A[M][K](bf16) * B[N][K]^T(bf16) + bias ----------------
template<typename OutT>
__global__ __launch_bounds__(256) void gemm_bt(
    const u16* __restrict__ A, const u16* __restrict__ B,
    const float* __restrict__ bias, OutT* __restrict__ C,
    int M, int N, int K)
{
  constexpr int LDT = 72;              // padded row stride (elements) -> conflict-minimal b128
  __shared__ u16 As[128 * LDT];
  __shared__ u16 Bs[128 * LDT];
  const int bm = blockIdx.y, bn = blockIdx.x;
  const int tid = threadIdx.x;
  const int lane = tid & 63;
  const int wv = tid >> 6;
  const int wm = wv >> 1, wn = wv & 1;  // 2x2 wave grid, each wave 64x64
  const int g = lane >> 4, qn = lane & 15;

  f32x4 acc[4][4];
  #pragma unroll
  for (int i = 0; i < 4; ++i)
    #pragma unroll
    for (int j = 0; j < 4; ++j) acc[i][j] = (f32x4){0.f, 0.f, 0.f, 0.f};

  const u16* Ab = A + (size_t)bm * 128 * K;
  const u16* Bb = B + (size_t)bn * 128 * K;

  for (int kt = 0; kt < K; kt += 64) {
    __syncthreads();
    #pragma unroll
    for (int i = 0; i < 4; ++i) {       // stage A,B tiles 128x64 each
      int u = tid + 256 * i;
      int row = u >> 3, c = u & 7;
      uint4 va = *reinterpret_cast<const uint4*>(Ab + (size_t)row * K + kt + c * 8);
      *reinterpret_cast<uint4*>(As + row * LDT + c * 8) = va;
      uint4 vb = *reinterpret_cast<const uint4*>(Bb + (size_t)row * K + kt + c * 8);
      *reinterpret_cast<uint4*>(Bs + row * LDT + c * 8) = vb;
    }
    __syncthreads();
    #pragma unroll
    for (int ks = 0; ks < 2; ++ks) {
      bf16x8 af[4], bfr[4];
      #pragma unroll
      for (int mi = 0; mi < 4; ++mi)
        af[mi] = *reinterpret_cast<const bf16x8*>(As + (wm * 64 + mi * 16 + qn) * LDT + g * 8 + ks * 32);
      #pragma unroll
      for (int ni = 0; ni < 4; ++ni)
        bfr[ni] = *reinterpret_cast<const bf16x8*>(Bs + (wn * 64 + ni * 16 + qn) * LDT + g * 8 + ks * 32);
      #pragma unroll
      for (int mi = 0; mi < 4; ++mi)
        #pragma unroll
        for (int ni = 0; ni < 4; ++ni)
          acc[mi][ni] = MFMA_BF16(af[mi], bfr[ni], acc[mi][ni]);
    }
  }
  // epilogue: C/D layout col=lane&15, row=(lane>>4)*4+reg
  #pragma unroll
  for (int ni = 0; ni < 4; ++ni) {
    int col = bn * 128 + wn * 64 + ni * 16 + qn;
    float bs = bias[col];
    #pragma unroll
    for (int mi = 0; mi < 4; ++mi) {
      #pragma unroll
      for (int r = 0; r < 4; ++r) {
        int row = bm * 128 + wm * 64 + mi * 16 + g * 4 + r;
        float v = acc[mi][ni][r] + bs;
        if constexpr (sizeof(OutT) == 2) C[(size_t)row * N + col] = (OutT)f2bf(v);
        else                             C[(size_t)row * N + col] = v;
      }
    }
  }
}

// ---------------- RoPE (in-place on bf16 [tok][heads*64]) ----------------
__global__ __launch_bounds__(256) void rope_kernel(
    u16* __restrict__ T, const float* __restrict__ cosT, const float* __restrict__ sinT,
    int heads8, int n8)
{
  int i = blockIdx.x * 256 + threadIdx.x;
  if (i >= n8) return;
  int tok = i / heads8;
  int r = i - tok * heads8;
  int d0 = (r & 7) * 8;                 // within-head dim offset
  int s = tok & 2047;                   // S = 2048
  uint4 v = reinterpret_cast<uint4*>(T)[i];
  u16* e = reinterpret_cast<u16*>(&v);
  float4 c = *reinterpret_cast<const float4*>(cosT + s * 32 + d0 / 2);
  float4 sn = *reinterpret_cast<const float4*>(sinT + s * 32 + d0 / 2);
  float cc[4] = {c.x, c.y, c.z, c.w}, ss[4] = {sn.x, sn.y, sn.z, sn.w};
  #pragma unroll
  for (int j = 0; j < 4; ++j) {
    float tr = bf2f(e[2 * j]), ti = bf2f(e[2 * j + 1]);
    e[2 * j]     = f2bf(tr * cc[j] - ti * ss[j]);
    e[2 * j + 1] = f2bf(tr * ss[j] + ti * cc[j]);
  }
  reinterpret_cast<uint4*>(T)[i] = v;
}

// ---------------- causal GQA flash attention ----------------
// grid: (qtile=32, hq=32, b=4); block 256 (4 waves, 16 q-rows each), KBLK=64
__global__ __launch_bounds__(256) void attn_kernel(
    const u16* __restrict__ Q, const u16* __restrict__ Kb,
    const u16* __restrict__ Vb, u16* __restrict__ O)
{
  constexpr int LDK = 72;
  constexpr float SCALE = 0.02209708691207961f; // 1/sqrt(2048)
  __shared__ u16 Kl[64 * LDK];
  __shared__ u16 Vt[64 * LDK];       // V transposed: [d][kpos]
  __shared__ u16 Pl[4][16 * LDK];    // per-wave P tile [q][kpos]
  const int qt = blockIdx.x, hq = blockIdx.y, b = blockIdx.z;
  const int kvh = hq >> 2;           // G = 4
  const int tid = threadIdx.x, lane = tid & 63, w = tid >> 6;
  const int g = lane >> 4, qn = lane & 15;
  const int q_g = qt * 64 + w * 16 + qn;

  const u16* qrow = Q + ((size_t)(b * 2048 + q_g) * 2048 + hq * 64);
  bf16x8 qf[2];
  qf[0] = *reinterpret_cast<const bf16x8*>(qrow + g * 8);
  qf[1] = *reinterpret_cast<const bf16x8*>(qrow + g * 8 + 32);

  float m = -1e30f, l = 0.f;
  f32x4 oa[4];
  #pragma unroll
  for (int i = 0; i < 4; ++i) oa[i] = (f32x4){0.f, 0.f, 0.f, 0.f};

  const u16* Kbase = Kb + ((size_t)b * 2048 * 512 + kvh * 64);
  const u16* Vbase = Vb + ((size_t)b * 2048 * 512 + kvh * 64);

  const int nkt = qt + 1;
  for (int kt = 0; kt < nkt; ++kt) {
    __syncthreads();
    // stage K tile [64 kpos][64 d]
    #pragma unroll
    for (int i = 0; i < 2; ++i) {
      int u = tid + 256 * i;
      int row = u >> 3, c = u & 7;
      uint4 v = *reinterpret_cast<const uint4*>(Kbase + (size_t)(kt * 64 + row) * 512 + c * 8);
      *reinterpret_cast<uint4*>(Kl + row * LDK + c * 8) = v;
    }
    // stage V^T tile: [d][kpos]
    #pragma unroll
    for (int i = 0; i < 2; ++i) {
      int u = tid + 256 * i;
      int rc = u >> 6, d = u & 63;
      uint4 pack;
      u16* tmp = reinterpret_cast<u16*>(&pack);
      #pragma unroll
      for (int j = 0; j < 8; ++j)
        tmp[j] = Vbase[(size_t)(kt * 64 + rc * 8 + j) * 512 + d];
      *reinterpret_cast<uint4*>(Vt + d * LDK + rc * 8) = pack;
    }
    __syncthreads();
    // S^T = K * Q^T : C row = kpos_local, col = q
    f32x4 st[4];
    #pragma unroll
    for (int cf = 0; cf < 4; ++cf) st[cf] = (f32x4){0.f, 0.f, 0.f, 0.f};
    #pragma unroll
    for (int ks = 0; ks < 2; ++ks) {
      #pragma unroll
      for (int cf = 0; cf < 4; ++cf) {
        bf16x8 kf = *reinterpret_cast<const bf16x8*>(Kl + (cf * 16 + qn) * LDK + g * 8 + ks * 32);
        st[cf] = MFMA_BF16(kf, qf[ks], st[cf]);
      }
    }
    // online softmax (per q row: lanes {qn, qn+16, qn+32, qn+48} hold its 64 kpos)
    float pv[16];
    float tmax = -1e30f;
    #pragma unroll
    for (int cf = 0; cf < 4; ++cf) {
      #pragma unroll
      for (int r = 0; r < 4; ++r) {
        int kp = kt * 64 + cf * 16 + g * 4 + r;
        float s = st[cf][r] * SCALE;
        if (kp > q_g) s = -1e30f;
        pv[cf * 4 + r] = s;
        tmax = fmaxf(tmax, s);
      }
    }
    tmax = fmaxf(tmax, __shfl_xor(tmax, 16));
    tmax = fmaxf(tmax, __shfl_xor(tmax, 32));
    float mnew = fmaxf(m, tmax);
    float fac = __expf(m - mnew);
    float lsum = 0.f;
    #pragma unroll
    for (int i = 0; i < 16; ++i) { float p = __expf(pv[i] - mnew); pv[i] = p; lsum += p; }
    lsum += __shfl_xor(lsum, 16);
    lsum += __shfl_xor(lsum, 32);
    l = l * fac + lsum;
    m = mnew;
    // rescale O accumulators (per-row factor via shuffle)
    #pragma unroll
    for (int r = 0; r < 4; ++r) {
      float fr = __shfl(fac, (lane & 48) | (g * 4 + r));
      #pragma unroll
      for (int df = 0; df < 4; ++df) oa[df][r] *= fr;
    }
    // write P to per-wave LDS tile [q][kpos] (bf16, packed pairs)
    u16* Pw = Pl[w];
    #pragma unroll
    for (int cf = 0; cf < 4; ++cf) {
      #pragma unroll
      for (int h = 0; h < 2; ++h) {
        uint32_t pk = (uint32_t)f2bf(pv[cf * 4 + 2 * h]) | ((uint32_t)f2bf(pv[cf * 4 + 2 * h + 1]) << 16);
        *reinterpret_cast<uint32_t*>(Pw + qn * LDK + cf * 16 + g * 4 + 2 * h) = pk;
      }
    }
    __syncthreads();
    // O += P * V
    #pragma unroll
    for (int ks = 0; ks < 2; ++ks) {
      bf16x8 pa = *reinterpret_cast<const bf16x8*>(Pw + qn * LDK + g * 8 + ks * 32);
      #pragma unroll
      for (int df = 0; df < 4; ++df) {
        bf16x8 vf = *reinterpret_cast<const bf16x8*>(Vt + (df * 16 + qn) * LDK + g * 8 + ks * 32);
        oa[df] = MFMA_BF16(pa, vf, oa[df]);
      }
    }
  }
  // epilogue: normalize rows, store O bf16 at [b][q][hq*64+d]
  #pragma unroll
  for (int r = 0; r < 4; ++r) {
    float lr = __shfl(l, (lane & 48) | (g * 4 + r));
    float inv = 1.f / lr;
    int row_g = qt * 64 + w * 16 + g * 4 + r;
    u16* orow = O + ((size_t)(b * 2048 + row_g) * 2048 + hq * 64);
    #pragma unroll
    for (int df = 0; df < 4; ++df)
      orow[df * 16 + qn] = f2bf(oa[df][r] * inv);
  }
}

// ---------------- launch ----------------
// Workspace layout (lifetime-aliased, peak 96,468,992 B):
//   [0,        33.5M)  x_bf   (dead after QKV GEMMs)  -> reused as Ob (attn output)
//   [33.5M,    67.1M)  Qb
//   [67.1M,    75.5M)  Kb
//   [75.5M,    83.9M)  Vb
//   [83.9M,    92.3M)  Wbuf: wq_bf (dead after Q GEMM) -> reused as wo_bf
//   [92.3M,    94.4M)  wk_bf
//   [94.4M,    96.5M)  wv_bf
extern "C" void kernel_launch(void* const* d_in, const int* in_sizes, int n_in,
                              void* d_out, int out_size, void* d_ws, size_t ws_size,
                              hipStream_t stream) {
  const float* x    = (const float*)d_in[0];
  const float* fc   = (const float*)d_in[1];
  const float* fs   = (const float*)d_in[2];
  const float* wq_w = (const float*)d_in[3];
  const float* wq_b = (const float*)d_in[4];
  const float* wk_w = (const float*)d_in[5];
  const float* wk_b = (const float*)d_in[6];
  const float* wv_w = (const float*)d_in[7];
  const float* wv_b = (const float*)d_in[8];
  const float* wo_w = (const float*)d_in[9];
  const float* wo_b = (const float*)d_in[10];
  float* out = (float*)d_out;
  char* ws = (char*)d_ws;

  const size_t NEEDED = 96468992;
  if (ws_size < NEEDED) return;   // signals via clean wrong-answer instead of memory fault

  u16* x_bf  = (u16*)(ws);                 // 33,554,432 B ; later aliased as Ob
  u16* Qb    = (u16*)(ws + 33554432);      // 33,554,432
  u16* Kb    = (u16*)(ws + 67108864);      //  8,388,608
  u16* Vb    = (u16*)(ws + 75497472);      //  8,388,608
  u16* Wbuf  = (u16*)(ws + 83886080);      //  8,388,608 ; wq_bf then wo_bf
  u16* wk_bf = (u16*)(ws + 92274688);      //  2,097,152
  u16* wv_bf = (u16*)(ws + 94371840);      //  2,097,152
  u16* Ob    = x_bf;                       // alias (x_bf dead after QKV GEMMs)

  // fp32 -> bf16 (x + QKV weights)
  cvt_kernel<<<16384, 256, 0, stream>>>(x,    x_bf, 4194304);
  cvt_kernel<<< 4096, 256, 0, stream>>>(wq_w, Wbuf, 1048576);
  cvt_kernel<<< 1024, 256, 0, stream>>>(wk_w, wk_bf, 262144);
  cvt_kernel<<< 1024, 256, 0, stream>>>(wv_w, wv_bf, 262144);

  // QKV projections
  gemm_bt<u16><<<dim3(16, 64), 256, 0, stream>>>(x_bf, Wbuf,  wq_b, Qb, 8192, 2048, 2048);
  gemm_bt<u16><<<dim3( 4, 64), 256, 0, stream>>>(x_bf, wk_bf, wk_b, Kb, 8192,  512, 2048);
  gemm_bt<u16><<<dim3( 4, 64), 256, 0, stream>>>(x_bf, wv_bf, wv_b, Vb, 8192,  512, 2048);

  // wo conversion into Wbuf (stream-serial: wq no longer needed)
  cvt_kernel<<< 4096, 256, 0, stream>>>(wo_w, Wbuf, 1048576);

  // RoPE on Q and K
  rope_kernel<<<8192, 256, 0, stream>>>(Qb, fc, fs, 256, 2097152);
  rope_kernel<<<2048, 256, 0, stream>>>(Kb, fc, fs,  64,  524288);

  // attention (writes Ob, which aliases the dead x_bf)
  attn_kernel<<<dim3(32, 32, 4), 256, 0, stream>>>(Qb, Kb, Vb, Ob);

  // output projection (fp32 out + bias)
  gemm_bt<float><<<dim3(16, 64), 256, 0, stream>>>(Ob, Wbuf, wo_b, out, 8192, 2048, 2048);
}